// Round 1
// baseline (218.797 us; speedup 1.0000x reference)
//
#include <hip/hip_runtime.h>

// LIF recurrence over last (time) dim, T=8, fp32 in/out. 4,194,304 neurons.
//   u_t = TAU * u_{t-1} * (1 - o_{t-1}) + x_t ;  o_t = (u_t > VTH) ? 1 : 0
//
// Memory-bound: 134 MB read + 134 MB write -> ~43 us floor at ~6.3 TB/s.
// Unit-stride float4 load/store per lane; a neuron's two time-halves live in
// adjacent lanes (pair 2n/2n+1 of the same wave), so the recurrence carry is
// exchanged in-register via __shfl_xor(1) -- no LDS, no barriers.
//   pass 1: all lanes run their 4 steps from (u,o)=(0,0)   (valid for even lanes)
//   xchg  : odd lanes take partner's (u,o) as carry; even lanes take (0,0)
//   pass 2: all lanes re-run their 4 steps with the correct carry and emit spikes
//
// This revision: 4 chunks per thread (64 B/lane in flight, 4 independent
// loads issued before any compute), grid 32768 -> 8192 blocks. Pure-ILP /
// launch-granularity change; algorithm and per-instruction coalescing are
// identical to the previous version.

#define LIF_TAU 0.25f
#define LIF_VTH 0.3f
#define BLOCK 256
#define ITERS 4   // float4 chunks per thread; block owns 16 KB contiguous

typedef float v4f __attribute__((ext_vector_type(4)));

__global__ __launch_bounds__(BLOCK) void lif_spike_kernel(
    const float* __restrict__ x, float* __restrict__ out) {
    // chunk k for this thread: vec4 index base + k*BLOCK
    // (BLOCK stride is even, so vec4-index parity == lane parity for every
    //  chunk, preserving the even/odd neuron-pair mapping.)
    const size_t base = (size_t)blockIdx.x * (BLOCK * ITERS) + threadIdx.x;

    const v4f* __restrict__ xv = reinterpret_cast<const v4f*>(x);
    v4f* __restrict__ ov = reinterpret_cast<v4f*>(out);

    // Issue all 4 independent 16 B loads first -> 4 outstanding vmem ops/lane.
    v4f v0 = __builtin_nontemporal_load(xv + base + 0 * BLOCK);
    v4f v1 = __builtin_nontemporal_load(xv + base + 1 * BLOCK);
    v4f v2 = __builtin_nontemporal_load(xv + base + 2 * BLOCK);
    v4f v3 = __builtin_nontemporal_load(xv + base + 3 * BLOCK);

    const bool odd = (threadIdx.x & 1) != 0;

    v4f w0, w1, w2, w3;

#define LIF_CHUNK(vv, ww)                                   \
    do {                                                    \
        float u = 0.0f, o = 0.0f;                           \
        _Pragma("unroll")                                   \
        for (int k = 0; k < 4; ++k) {                       \
            u = LIF_TAU * u * (1.0f - o) + (vv)[k];         \
            o = (u > LIF_VTH) ? 1.0f : 0.0f;                \
        }                                                   \
        float cu = __shfl_xor(u, 1);                        \
        float co = __shfl_xor(o, 1);                        \
        u = odd ? cu : 0.0f;                                \
        o = odd ? co : 0.0f;                                \
        _Pragma("unroll")                                   \
        for (int k = 0; k < 4; ++k) {                       \
            u = LIF_TAU * u * (1.0f - o) + (vv)[k];         \
            o = (u > LIF_VTH) ? 1.0f : 0.0f;                \
            (ww)[k] = o;                                    \
        }                                                   \
    } while (0)

    LIF_CHUNK(v0, w0);
    LIF_CHUNK(v1, w1);
    LIF_CHUNK(v2, w2);
    LIF_CHUNK(v3, w3);

#undef LIF_CHUNK

    __builtin_nontemporal_store(w0, ov + base + 0 * BLOCK);
    __builtin_nontemporal_store(w1, ov + base + 1 * BLOCK);
    __builtin_nontemporal_store(w2, ov + base + 2 * BLOCK);
    __builtin_nontemporal_store(w3, ov + base + 3 * BLOCK);
}

extern "C" void kernel_launch(void* const* d_in, const int* in_sizes, int n_in,
                              void* d_out, int out_size, void* d_ws, size_t ws_size,
                              hipStream_t stream) {
    const float* x = (const float*)d_in[0];
    float* out = (float*)d_out;
    int n_elems = in_sizes[0];                 // 33,554,432
    int n_vec4 = n_elems / 4;                  // 8,388,608 float4s
    int n_blocks = n_vec4 / (BLOCK * ITERS);   // 8,192 blocks, 16 KB each

    lif_spike_kernel<<<n_blocks, BLOCK, 0, stream>>>(x, out);
}